// Round 2
// baseline (138.259 us; speedup 1.0000x reference)
//
#include <hip/hip_runtime.h>

// Problem constants (fixed by the reference)
#define NNZ_  524288
#define S_    8192
#define OUT_  8192
#define CAP   192     // per-column bucket capacity; counts ~ Poisson(64), 192 is ~12 sigma

// Pass 1: bucket triples by column.  cnt[c] = #entries in column c,
// buckets[c][p] = original triple index i (order within bucket irrelevant;
// we dedupe by comparing original indices directly).
__global__ void __launch_bounds__(256) scatter_kernel(
    const int* __restrict__ cols, int* __restrict__ cnt, int* __restrict__ buckets) {
    int i = blockIdx.x * blockDim.x + threadIdx.x;
    if (i >= NNZ_) return;
    int c = cols[i];
    int p = atomicAdd(&cnt[c], 1);
    if (p < CAP) buckets[c * CAP + p] = i;
}

// Pass 2: one 64-lane wave per output column.
// Winner rule (numpy last-write-wins): entry i with row r wins iff no entry
// in the same column has the same row and a LARGER original index.
__global__ void __launch_bounds__(256) col_kernel(
    const float* __restrict__ x, const float* __restrict__ W,
    const float* __restrict__ b, const int* __restrict__ rows,
    const int* __restrict__ wpos, const int* __restrict__ bias_pos,
    const int* __restrict__ cnt, const int* __restrict__ buckets,
    float* __restrict__ out) {
    __shared__ int srow[4][CAP];
    __shared__ int sidx[4][CAP];
    const int wave = threadIdx.x >> 6;   // 4 waves per block
    const int lane = threadIdx.x & 63;
    const int c = blockIdx.x * 4 + wave; // grid = OUT_/4 blocks -> c in [0, OUT_)

    int k = cnt[c];
    if (k > CAP) k = CAP;

    // Stage this column's (row, orig_idx) pairs in LDS
    for (int m = lane; m < k; m += 64) {
        int i = buckets[c * CAP + m];
        sidx[wave][m] = i;
        srow[wave][m] = rows[i];
    }
    __syncthreads();  // uniform: every thread reaches exactly once

    float acc = 0.f;
    for (int m = lane; m < k; m += 64) {
        int i = sidx[wave][m];
        int r = srow[wave][m];
        bool win = true;
        for (int t = 0; t < k; ++t) {
            if (srow[wave][t] == r && sidx[wave][t] > i) { win = false; break; }
        }
        if (win) acc += x[r] * W[wpos[i]];
    }

    // Wave reduction (64 lanes)
    for (int off = 32; off; off >>= 1) acc += __shfl_down(acc, off, 64);
    if (lane == 0) out[c] = acc + b[bias_pos[c]];
}

extern "C" void kernel_launch(void* const* d_in, const int* in_sizes, int n_in,
                              void* d_out, int out_size, void* d_ws, size_t ws_size,
                              hipStream_t stream) {
    const float* x    = (const float*)d_in[0];
    const float* Pw   = (const float*)d_in[1];
    const float* Pb   = (const float*)d_in[2];
    const int*   rows = (const int*)d_in[3];
    const int*   cols = (const int*)d_in[4];
    const int*   wpos = (const int*)d_in[5];
    const int*   bpos = (const int*)d_in[6];
    float*       out  = (float*)d_out;

    // Workspace layout: cnt[OUT_] | buckets[OUT_][CAP]   (~6.03 MB)
    int* cnt     = (int*)d_ws;
    int* buckets = cnt + OUT_;

    hipMemsetAsync(cnt, 0, OUT_ * sizeof(int), stream);
    scatter_kernel<<<NNZ_ / 256, 256, 0, stream>>>(cols, cnt, buckets);
    col_kernel<<<OUT_ / 4, 256, 0, stream>>>(x, Pw, Pb, rows, wpos, bpos, cnt, buckets, out);
}